// Round 1
// baseline (107.858 us; speedup 1.0000x reference)
//
#include <hip/hip_runtime.h>
#include <math.h>

#define MN 8192
#define ME 16384
#define D  256
#define DE 128

// output layout (float32 elements)
#define OFF_NEWNODES 0
#define OFF_NEWEDGES (MN*D)                     // 2097152
#define OFF_NREC     (MN*D + ME*DE)             // 4194304
#define OFF_NSEND    (OFF_NREC + ME)            // 4210688
#define OFF_NAN      (OFF_NSEND + ME)           // 4227072
#define OFF_NAE      (OFF_NAN + MN)             // 4235264

// ws layout (int32): [0,MN) divs | [MN,2MN) map(rank->node) | [2MN, 2MN+8) scalars
// scalars: 0=n_active 1=n_edges 2=n_divs_raw 3=n_divs

__global__ __launch_bounds__(256) void k_divs(
    const float* __restrict__ nodes, const float* __restrict__ W,
    const float* __restrict__ b, const float* __restrict__ active,
    const float* __restrict__ u, int* __restrict__ divs)
{
    int wave = threadIdx.x >> 6;
    int lane = threadIdx.x & 63;
    int node = blockIdx.x * 4 + wave;
    const float4* n4 = reinterpret_cast<const float4*>(nodes) + node * (D / 4);
    const float4* w4 = reinterpret_cast<const float4*>(W);
    float4 v = n4[lane];
    float4 w = w4[lane];
    double s = (double)v.x * (double)w.x + (double)v.y * (double)w.y +
               (double)v.z * (double)w.z + (double)v.w * (double)w.w;
    #pragma unroll
    for (int off = 32; off >= 1; off >>= 1)
        s += __shfl_xor(s, off, 64);
    if (lane == 0) {
        double x = s + (double)b[0];
        double p = 1.0 / (1.0 + exp(-x));
        p *= (double)active[node];
        divs[node] = ((double)u[node] < p) ? 1 : 0;
    }
}

__global__ __launch_bounds__(1024) void k_scan(
    const float* __restrict__ active_nodes, const float* __restrict__ active_edges,
    const int* __restrict__ divs, int* __restrict__ map, int* __restrict__ scalars)
{
    __shared__ int sdata[1024];
    __shared__ float fdata[1024];
    int tid = threadIdx.x;
    int base = tid * 8;
    int d[8];
    int loc = 0;
    #pragma unroll
    for (int k = 0; k < 8; k++) { d[k] = divs[base + k]; loc += d[k]; }
    sdata[tid] = loc;
    __syncthreads();
    // inclusive Hillis-Steele scan over 1024 thread sums
    for (int off = 1; off < 1024; off <<= 1) {
        int v = (tid >= off) ? sdata[tid - off] : 0;
        __syncthreads();
        sdata[tid] += v;
        __syncthreads();
    }
    int excl = sdata[tid] - loc;      // exclusive prefix over thread chunks
    int total = sdata[1023];
    __syncthreads();
    // n_active
    float fa = 0.f;
    #pragma unroll
    for (int k = 0; k < 8; k++) fa += active_nodes[base + k];
    fdata[tid] = fa;
    __syncthreads();
    for (int off = 512; off >= 1; off >>= 1) {
        if (tid < off) fdata[tid] += fdata[tid + off];
        __syncthreads();
    }
    int n_active = (int)(fdata[0] + 0.5f);
    __syncthreads();
    // n_edges
    float fe = 0.f;
    #pragma unroll
    for (int k = 0; k < 16; k++) fe += active_edges[tid * 16 + k];
    fdata[tid] = fe;
    __syncthreads();
    for (int off = 512; off >= 1; off >>= 1) {
        if (tid < off) fdata[tid] += fdata[tid + off];
        __syncthreads();
    }
    int n_edges = (int)(fdata[0] + 0.5f);
    // map: rank -> node id
    int r = excl;
    #pragma unroll
    for (int k = 0; k < 8; k++) {
        if (d[k]) { map[r] = base + k; r++; }
    }
    if (tid == 0) {
        int allowed = MN - n_active - 1;
        int nd = total;
        if (nd > allowed) nd = allowed;
        if (nd < 0) nd = 0;
        scalars[0] = n_active;
        scalars[1] = n_edges;
        scalars[2] = total;
        scalars[3] = nd;
    }
}

__global__ __launch_bounds__(256) void k_write(
    const float* __restrict__ nodes, const float* __restrict__ edges,
    const int* __restrict__ receivers, const int* __restrict__ senders,
    const float* __restrict__ noise_nodes, const float* __restrict__ noise_edges,
    const int* __restrict__ map, const int* __restrict__ scalars,
    float* __restrict__ out)
{
    const int NN4  = MN * D / 4;     // 524288 float4 units
    const int NED4 = ME * DE / 4;    // 524288
    const int VEC  = NN4 + NED4;     // 1048576
    int idx = blockIdx.x * 256 + threadIdx.x;
    int n_active = scalars[0];
    int n_edges  = scalars[1];
    int nd_raw   = scalars[2];
    int nd       = scalars[3];

    if (idx < NN4) {
        int row = idx >> 6;          // D/4 = 64 float4 per row
        float4 v = reinterpret_cast<const float4*>(nodes)[idx];
        if (row >= n_active && row < n_active + nd) {
            float4 nz = reinterpret_cast<const float4*>(noise_nodes)[idx];
            v.x += nz.x; v.y += nz.y; v.z += nz.z; v.w += nz.w;
        }
        reinterpret_cast<float4*>(out)[idx] = v;
    } else if (idx < VEC) {
        int j = idx - NN4;
        int row = j >> 5;            // DE/4 = 32 float4 per row
        float4 v = reinterpret_cast<const float4*>(edges)[j];
        if (row >= n_edges && row < n_edges + nd) {
            float4 nz = reinterpret_cast<const float4*>(noise_edges)[j];
            v.x += nz.x; v.y += nz.y; v.z += nz.z; v.w += nz.w;
        }
        reinterpret_cast<float4*>(out)[NN4 + j] = v;
    } else {
        int s = idx - VEC;
        if (s < ME) {                              // nrec
            int j = s;
            bool isnew = (j >= n_edges) && (j < n_edges + nd);
            float val = isnew ? (float)(n_active + (j - n_edges)) : (float)receivers[j];
            out[OFF_NREC + j] = val;
        } else if (s < 2 * ME) {                   // nsend
            int j = s - ME;
            bool isnew = (j >= n_edges) && (j < n_edges + nd);
            float val = isnew ? 0.0f : (float)senders[j];
            int r = j - n_edges;
            if (r >= 0 && r < nd_raw) val += (float)map[r];
            out[OFF_NSEND + j] = val;
        } else if (s < 2 * ME + MN) {              // nanodes
            int i = s - 2 * ME;
            int lim = n_active + nd;
            if (lim > MN) lim = MN;
            out[OFF_NAN + i] = (i < lim && i != MN - 1) ? 1.0f : 0.0f;
        } else {                                   // naedges
            int j = s - 2 * ME - MN;
            int lim = n_edges + nd;
            if (lim > ME) lim = ME;
            out[OFF_NAE + j] = (j < lim && j != ME - 1) ? 1.0f : 0.0f;
        }
    }
}

extern "C" void kernel_launch(void* const* d_in, const int* in_sizes, int n_in,
                              void* d_out, int out_size, void* d_ws, size_t ws_size,
                              hipStream_t stream) {
    const float* nodes        = (const float*)d_in[0];
    const float* edges        = (const float*)d_in[1];
    const int*   receivers    = (const int*)d_in[2];
    const int*   senders      = (const int*)d_in[3];
    const float* active_nodes = (const float*)d_in[4];
    const float* active_edges = (const float*)d_in[5];
    const float* W            = (const float*)d_in[6];
    const float* b            = (const float*)d_in[7];
    const float* u_div        = (const float*)d_in[8];
    const float* noise_nodes  = (const float*)d_in[9];
    const float* noise_edges  = (const float*)d_in[10];
    float* out = (float*)d_out;

    int* ws      = (int*)d_ws;
    int* divs    = ws;
    int* map     = ws + MN;
    int* scalars = ws + 2 * MN;

    hipLaunchKernelGGL(k_divs, dim3(MN / 4), dim3(256), 0, stream,
                       nodes, W, b, active_nodes, u_div, divs);
    hipLaunchKernelGGL(k_scan, dim3(1), dim3(1024), 0, stream,
                       active_nodes, active_edges, divs, map, scalars);
    const int NN4 = MN * D / 4, NED4 = ME * DE / 4;
    const int total_items = NN4 + NED4 + 2 * ME + MN + ME;
    hipLaunchKernelGGL(k_write, dim3((total_items + 255) / 256), dim3(256), 0, stream,
                       nodes, edges, receivers, senders, noise_nodes, noise_edges,
                       map, scalars, out);
}

// Round 2
// 104.820 us; speedup vs baseline: 1.0290x; 1.0290x over previous
//
#include <hip/hip_runtime.h>
#include <math.h>

#define MN 8192
#define ME 16384
#define D  256
#define DE 128

// output layout (float32 elements)
#define OFF_NEWNODES 0
#define OFF_NEWEDGES (MN*D)                     // 2097152
#define OFF_NREC     (MN*D + ME*DE)             // 4194304
#define OFF_NSEND    (OFF_NREC + ME)            // 4210688
#define OFF_NAN      (OFF_NSEND + ME)           // 4227072
#define OFF_NAE      (OFF_NAN + MN)             // 4235264

// ws layout (int32): [0,MN) divs | [MN,2MN) map(rank->node) | [2MN, 2MN+8) scalars
// scalars: 0=n_active 1=n_edges 2=n_divs_raw 3=n_divs

__global__ __launch_bounds__(256) void k_divs(
    const float* __restrict__ nodes, const float* __restrict__ W,
    const float* __restrict__ b, const float* __restrict__ active,
    const float* __restrict__ u, int* __restrict__ divs)
{
    int wave = threadIdx.x >> 6;
    int lane = threadIdx.x & 63;
    int node = blockIdx.x * 4 + wave;
    const float4* n4 = reinterpret_cast<const float4*>(nodes) + node * (D / 4);
    const float4* w4 = reinterpret_cast<const float4*>(W);
    float4 v = n4[lane];
    float4 w = w4[lane];
    // f64 dot: keeps p within ~1 ulp of the f32 reference's value so the
    // u < p decision can't flip (a flip cascades into O(1e3) absmax).
    double s = (double)v.x * (double)w.x + (double)v.y * (double)w.y +
               (double)v.z * (double)w.z + (double)v.w * (double)w.w;
    #pragma unroll
    for (int off = 32; off >= 1; off >>= 1)
        s += __shfl_xor(s, off, 64);
    if (lane == 0) {
        double x = s + (double)b[0];
        double p = 1.0 / (1.0 + exp(-x));
        p *= (double)active[node];
        divs[node] = ((double)u[node] < p) ? 1 : 0;
    }
}

// 1024 threads, one block. 2 barriers total (was 20+ with Hillis-Steele).
__global__ __launch_bounds__(1024) void k_scan(
    const float* __restrict__ active_nodes, const float* __restrict__ active_edges,
    const int* __restrict__ divs, int* __restrict__ map, int* __restrict__ scalars)
{
    __shared__ int   wsum[16];
    __shared__ float wfa[16];
    __shared__ float wfe[16];
    __shared__ int   s_na, s_ne;

    int tid  = threadIdx.x;
    int lane = tid & 63;
    int wave = tid >> 6;
    int base = tid * 8;

    // load 8 div flags per thread (two int4)
    const int4* d4 = reinterpret_cast<const int4*>(divs);
    int4 a  = d4[tid * 2];
    int4 b2 = d4[tid * 2 + 1];
    int d[8] = {a.x, a.y, a.z, a.w, b2.x, b2.y, b2.z, b2.w};
    int loc = 0;
    #pragma unroll
    for (int k = 0; k < 8; k++) loc += d[k];

    // wave-level inclusive scan of per-thread sums
    int s = loc;
    #pragma unroll
    for (int off = 1; off < 64; off <<= 1) {
        int v = __shfl_up(s, off, 64);
        if (lane >= off) s += v;
    }
    if (lane == 63) wsum[wave] = s;

    // n_active partial (8192 floats = 2048 float4, 2 per thread)
    const float4* an4 = reinterpret_cast<const float4*>(active_nodes);
    float4 fa0 = an4[tid * 2], fa1 = an4[tid * 2 + 1];
    float fa = fa0.x + fa0.y + fa0.z + fa0.w + fa1.x + fa1.y + fa1.z + fa1.w;
    #pragma unroll
    for (int off = 32; off >= 1; off >>= 1) fa += __shfl_xor(fa, off, 64);
    if (lane == 0) wfa[wave] = fa;

    // n_edges partial (16384 floats = 4096 float4, 4 per thread)
    const float4* ae4 = reinterpret_cast<const float4*>(active_edges);
    float fe = 0.f;
    #pragma unroll
    for (int k = 0; k < 4; k++) {
        float4 t = ae4[tid * 4 + k];
        fe += t.x + t.y + t.z + t.w;
    }
    #pragma unroll
    for (int off = 32; off >= 1; off >>= 1) fe += __shfl_xor(fe, off, 64);
    if (lane == 0) wfe[wave] = fe;

    __syncthreads();

    if (wave == 0) {
        // scan the 16 wave totals (lanes 0..15 hold data, others 0)
        int v = (lane < 16) ? wsum[lane] : 0;
        #pragma unroll
        for (int off = 1; off < 16; off <<= 1) {
            int u2 = __shfl_up(v, off, 64);
            if (lane >= off) v += u2;
        }
        if (lane < 16) wsum[lane] = v;   // now inclusive scan of wave totals
        float fav = (lane < 16) ? wfa[lane] : 0.f;
        float fev = (lane < 16) ? wfe[lane] : 0.f;
        #pragma unroll
        for (int off = 32; off >= 1; off >>= 1) {
            fav += __shfl_xor(fav, off, 64);
            fev += __shfl_xor(fev, off, 64);
        }
        if (lane == 0) { s_na = (int)(fav + 0.5f); s_ne = (int)(fev + 0.5f); }
    }
    __syncthreads();

    int wave_excl = (wave == 0) ? 0 : wsum[wave - 1];
    int excl  = wave_excl + (s - loc);   // exclusive prefix of this thread's chunk
    int total = wsum[15];

    int r = excl;
    #pragma unroll
    for (int k = 0; k < 8; k++)
        if (d[k]) { map[r] = base + k; r++; }

    if (tid == 0) {
        int n_active = s_na, n_edges = s_ne;
        int allowed = MN - n_active - 1;
        int nd = total;
        if (nd > allowed) nd = allowed;
        if (nd < 0) nd = 0;
        scalars[0] = n_active;
        scalars[1] = n_edges;
        scalars[2] = total;
        scalars[3] = nd;
    }
}

__global__ __launch_bounds__(256) void k_write(
    const float* __restrict__ nodes, const float* __restrict__ edges,
    const int* __restrict__ receivers, const int* __restrict__ senders,
    const float* __restrict__ noise_nodes, const float* __restrict__ noise_edges,
    const int* __restrict__ map, const int* __restrict__ scalars,
    float* __restrict__ out)
{
    const int NN4  = MN * D / 4;     // 524288 float4 units
    const int NED4 = ME * DE / 4;    // 524288
    const int VEC  = NN4 + NED4;     // 1048576
    int idx = blockIdx.x * 256 + threadIdx.x;
    int n_active = scalars[0];
    int n_edges  = scalars[1];
    int nd_raw   = scalars[2];
    int nd       = scalars[3];

    if (idx < NN4) {
        int row = idx >> 6;          // D/4 = 64 float4 per row
        float4 v = reinterpret_cast<const float4*>(nodes)[idx];
        if (row >= n_active && row < n_active + nd && row != MN - 1) {
            float4 nz = reinterpret_cast<const float4*>(noise_nodes)[idx];
            v.x += nz.x; v.y += nz.y; v.z += nz.z; v.w += nz.w;
        }
        reinterpret_cast<float4*>(out)[idx] = v;
    } else if (idx < VEC) {
        int j = idx - NN4;
        int row = j >> 5;            // DE/4 = 32 float4 per row
        float4 v = reinterpret_cast<const float4*>(edges)[j];
        if (row >= n_edges && row < n_edges + nd && row != ME - 1) {
            float4 nz = reinterpret_cast<const float4*>(noise_edges)[j];
            v.x += nz.x; v.y += nz.y; v.z += nz.z; v.w += nz.w;
        }
        reinterpret_cast<float4*>(out)[NN4 + j] = v;
    } else {
        int s = idx - VEC;
        if (s < ME) {                              // nrec
            int j = s;
            bool isnew = (j >= n_edges) && (j < n_edges + nd);
            float val = isnew ? (float)(n_active + (j - n_edges)) : (float)receivers[j];
            out[OFF_NREC + j] = val;
        } else if (s < 2 * ME) {                   // nsend
            int j = s - ME;
            bool isnew = (j >= n_edges) && (j < n_edges + nd);
            float val = isnew ? 0.0f : (float)senders[j];
            int r = j - n_edges;
            if (r >= 0 && r < nd_raw) val += (float)map[r];
            out[OFF_NSEND + j] = val;
        } else if (s < 2 * ME + MN) {              // nanodes
            int i = s - 2 * ME;
            int lim = n_active + nd;
            if (lim > MN) lim = MN;
            out[OFF_NAN + i] = (i < lim && i != MN - 1) ? 1.0f : 0.0f;
        } else {                                   // naedges
            int j = s - 2 * ME - MN;
            int lim = n_edges + nd;
            if (lim > ME) lim = ME;
            out[OFF_NAE + j] = (j < lim && j != ME - 1) ? 1.0f : 0.0f;
        }
    }
}

extern "C" void kernel_launch(void* const* d_in, const int* in_sizes, int n_in,
                              void* d_out, int out_size, void* d_ws, size_t ws_size,
                              hipStream_t stream) {
    const float* nodes        = (const float*)d_in[0];
    const float* edges        = (const float*)d_in[1];
    const int*   receivers    = (const int*)d_in[2];
    const int*   senders      = (const int*)d_in[3];
    const float* active_nodes = (const float*)d_in[4];
    const float* active_edges = (const float*)d_in[5];
    const float* W            = (const float*)d_in[6];
    const float* b            = (const float*)d_in[7];
    const float* u_div        = (const float*)d_in[8];
    const float* noise_nodes  = (const float*)d_in[9];
    const float* noise_edges  = (const float*)d_in[10];
    float* out = (float*)d_out;

    int* ws      = (int*)d_ws;
    int* divs    = ws;
    int* map     = ws + MN;
    int* scalars = ws + 2 * MN;

    hipLaunchKernelGGL(k_divs, dim3(MN / 4), dim3(256), 0, stream,
                       nodes, W, b, active_nodes, u_div, divs);
    hipLaunchKernelGGL(k_scan, dim3(1), dim3(1024), 0, stream,
                       active_nodes, active_edges, divs, map, scalars);
    const int NN4 = MN * D / 4, NED4 = ME * DE / 4;
    const int total_items = NN4 + NED4 + 2 * ME + MN + ME;
    hipLaunchKernelGGL(k_write, dim3((total_items + 255) / 256), dim3(256), 0, stream,
                       nodes, edges, receivers, senders, noise_nodes, noise_edges,
                       map, scalars, out);
}